// Round 3
// baseline (721.988 us; speedup 1.0000x reference)
//
#include <hip/hip_runtime.h>
#include <math.h>

#define DDIM 1024
#define BQ 256
#define EPSV 1e-8f
#define NCAND 48

typedef short bf16x8 __attribute__((ext_vector_type(8)));
typedef float f32x4 __attribute__((ext_vector_type(4)));

__device__ __forceinline__ unsigned short f2bf(float x) {
  union { float f; unsigned int u; } v;
  v.f = x;
  unsigned int lsb = (v.u >> 16) & 1u;
  v.u += 0x7fffu + lsb;  // round-to-nearest-even
  return (unsigned short)(v.u >> 16);
}
__device__ __forceinline__ float bf2f(unsigned short b) {
  union { unsigned int u; float f; } v;
  v.u = ((unsigned int)b) << 16;
  return v.f;
}
// packed fp32->bf16 (RNE), 1 instr for 2 elements: low16=bf16(lo), hi16=bf16(hi)
__device__ __forceinline__ unsigned int cvtpk_bf16(float lo, float hi) {
  unsigned int r;
  asm("v_cvt_pk_bf16_f32 %0, %1, %2" : "=v"(r) : "v"(lo), "v"(hi));
  return r;
}

// ---------------- prep: Q fp32 -> bf16 in MFMA-fragment order, qn ----------
// Qb layout: 16-B chunks. chunk = (t*16 + q/16)*64 + kquad*16 + (q&15),
// where t = k/32, kquad = (k/8)&3, elem = k&7. With this order, the gemm
// wave's fragment load group (t, g=w*4+i) has lane l reading chunk
// group*64 + l  == one contiguous, perfectly coalesced 1 KB per wave.
__global__ __launch_bounds__(256) void prep_q(const float* __restrict__ Q,
                                              unsigned short* __restrict__ Qb,
                                              float* __restrict__ qn) {
  int wave = threadIdx.x >> 6, lane = threadIdx.x & 63;
  int q = blockIdx.x * 4 + wave;
  const float4* src = (const float4*)(Q + (size_t)q * DDIM);
  int g = q >> 4, qrow = q & 15;
  float s = 0.f;
#pragma unroll
  for (int t4 = 0; t4 < 4; ++t4) {
    float4 v = src[t4 * 64 + lane];
    s += v.x * v.x + v.y * v.y + v.z * v.z + v.w * v.w;
    int k = t4 * 256 + lane * 4;
    int tt = k >> 5;
    int kquad = (k >> 3) & 3;
    int elem = k & 7;  // 0 or 4
    size_t chunk = (size_t)(tt * 16 + g) * 64 + kquad * 16 + qrow;
    ushort4 o;
    o.x = f2bf(v.x); o.y = f2bf(v.y); o.z = f2bf(v.z); o.w = f2bf(v.w);
    *(ushort4*)(Qb + chunk * 8 + elem) = o;
  }
#pragma unroll
  for (int o = 32; o > 0; o >>= 1) s += __shfl_down(s, o, 64);
  if (lane == 0) qn[q] = sqrtf(s);
}

// ---------------- MFMA GEMM: all 256 q x 64 n per block ----------------
// Q comes straight from L2-resident fragment-ordered Qb into registers
// (double-buffered, prefetched one step ahead) — NO Q LDS staging. LDS holds
// only the 64x32 M tile (double-buffered, 8 KB). One raw barrier per K-step;
// all global loads are compiler-visible so vmcnt waits are auto-counted and
// the in-flight prefetches (M(t+2) x2 + Q(t+1) x4) survive the barrier.
__global__ __launch_bounds__(256) void gemm_topk(
    const float* __restrict__ M, const unsigned short* __restrict__ Qb,
    unsigned short* __restrict__ sims, float* __restrict__ rmn,
    int N, int Npitch) {
  __shared__ unsigned short Ms[2][64 * 32];  // [buf][n][k]
  const int tid = threadIdx.x;
  const int wave = tid >> 6, lane = tid & 63;
  const int quad = lane >> 4, l15 = lane & 15;
  const int n0 = blockIdx.x * 64;

  const int mrow = tid >> 2;    // 0..63
  const int mchunk = tid & 3;   // 0..3, 8 floats each
  const bool mvalid = (n0 + mrow) < N;
  // invalid rows redirect to row 0: keeps vmem issue counts wave-uniform;
  // resulting sims at n>=N land in the pitch padding and are never read.
  const float* mptr = M + (size_t)(mvalid ? (n0 + mrow) : 0) * DDIM + mchunk * 8;

  // fragment pointer: afr(t, i) = qptr[t*1024 + i*64]
  const bf16x8* qptr = (const bf16x8*)Qb + (size_t)wave * 256 + lane;

  f32x4 acc[4][4];
#pragma unroll
  for (int i = 0; i < 4; ++i)
#pragma unroll
    for (int j = 0; j < 4; ++j) acc[i][j] = (f32x4){0.f, 0.f, 0.f, 0.f};
  float sumsq = 0.f;

  // prologue: Q(0) fragments + M(0), M(1) into named reg sets.
  bf16x8 aA0 = qptr[0], aA1 = qptr[64], aA2 = qptr[128], aA3 = qptr[192];
  bf16x8 aB0{}, aB1{}, aB2{}, aB3{};  // filled by body(0) before body(1) reads
  float4 mrA0 = *(const float4*)(mptr);
  float4 mrA1 = *(const float4*)(mptr + 4);
  float4 mrB0 = *(const float4*)(mptr + 32);
  float4 mrB1 = *(const float4*)(mptr + 36);

  auto body = [&](int t, int buf, float4& r0, float4& r1, bf16x8& c0,
                  bf16x8& c1, bf16x8& c2, bf16x8& c3, bf16x8& p0, bf16x8& p1,
                  bf16x8& p2, bf16x8& p3) {
    // ---- convert M(t) -> Ms[buf], sumsq, prefetch M(t+2) ----
    sumsq += r0.x * r0.x + r0.y * r0.y + r0.z * r0.z + r0.w * r0.w +
             r1.x * r1.x + r1.y * r1.y + r1.z * r1.z + r1.w * r1.w;
    uint4 packed;
    packed.x = cvtpk_bf16(r0.x, r0.y);
    packed.y = cvtpk_bf16(r0.z, r0.w);
    packed.z = cvtpk_bf16(r1.x, r1.y);
    packed.w = cvtpk_bf16(r1.z, r1.w);
    *(uint4*)&Ms[buf][mrow * 32 + mchunk * 8] = packed;
    int k2 = t * 32 + 64;
    const float* p = mptr + ((k2 < DDIM) ? k2 : 0);  // dummy keeps count uniform
    r0 = *(const float4*)(p);
    r1 = *(const float4*)(p + 4);
    // ---- Ms[buf] visible to all waves; prefetches stay in flight ----
    asm volatile("s_waitcnt lgkmcnt(0)" ::: "memory");
    __builtin_amdgcn_s_barrier();
    __builtin_amdgcn_sched_barrier(0);
    // ---- prefetch Q(t+1) fragments (dummy reload of group 0 at t=31) ----
    const bf16x8* qp = qptr + (size_t)((t + 1) & 31) * 1024;
    p0 = qp[0]; p1 = qp[64]; p2 = qp[128]; p3 = qp[192];
    // ---- compute on buf with current Q fragments ----
    bf16x8 bfr[4];
#pragma unroll
    for (int j = 0; j < 4; ++j)
      bfr[j] = *(const bf16x8*)&Ms[buf][(j * 16 + l15) * 32 + quad * 8];
    acc[0][0] = __builtin_amdgcn_mfma_f32_16x16x32_bf16(c0, bfr[0], acc[0][0], 0, 0, 0);
    acc[0][1] = __builtin_amdgcn_mfma_f32_16x16x32_bf16(c0, bfr[1], acc[0][1], 0, 0, 0);
    acc[0][2] = __builtin_amdgcn_mfma_f32_16x16x32_bf16(c0, bfr[2], acc[0][2], 0, 0, 0);
    acc[0][3] = __builtin_amdgcn_mfma_f32_16x16x32_bf16(c0, bfr[3], acc[0][3], 0, 0, 0);
    acc[1][0] = __builtin_amdgcn_mfma_f32_16x16x32_bf16(c1, bfr[0], acc[1][0], 0, 0, 0);
    acc[1][1] = __builtin_amdgcn_mfma_f32_16x16x32_bf16(c1, bfr[1], acc[1][1], 0, 0, 0);
    acc[1][2] = __builtin_amdgcn_mfma_f32_16x16x32_bf16(c1, bfr[2], acc[1][2], 0, 0, 0);
    acc[1][3] = __builtin_amdgcn_mfma_f32_16x16x32_bf16(c1, bfr[3], acc[1][3], 0, 0, 0);
    acc[2][0] = __builtin_amdgcn_mfma_f32_16x16x32_bf16(c2, bfr[0], acc[2][0], 0, 0, 0);
    acc[2][1] = __builtin_amdgcn_mfma_f32_16x16x32_bf16(c2, bfr[1], acc[2][1], 0, 0, 0);
    acc[2][2] = __builtin_amdgcn_mfma_f32_16x16x32_bf16(c2, bfr[2], acc[2][2], 0, 0, 0);
    acc[2][3] = __builtin_amdgcn_mfma_f32_16x16x32_bf16(c2, bfr[3], acc[2][3], 0, 0, 0);
    acc[3][0] = __builtin_amdgcn_mfma_f32_16x16x32_bf16(c3, bfr[0], acc[3][0], 0, 0, 0);
    acc[3][1] = __builtin_amdgcn_mfma_f32_16x16x32_bf16(c3, bfr[1], acc[3][1], 0, 0, 0);
    acc[3][2] = __builtin_amdgcn_mfma_f32_16x16x32_bf16(c3, bfr[2], acc[3][2], 0, 0, 0);
    acc[3][3] = __builtin_amdgcn_mfma_f32_16x16x32_bf16(c3, bfr[3], acc[3][3], 0, 0, 0);
  };

#pragma unroll 1
  for (int t = 0; t < 32; t += 2) {
    body(t, 0, mrA0, mrA1, aA0, aA1, aA2, aA3, aB0, aB1, aB2, aB3);
    body(t + 1, 1, mrB0, mrB1, aB0, aB1, aB2, aB3, aA0, aA1, aA2, aA3);
  }

  // 1/||m|| for this block's 64 rows (exact fp32 sums from staging data)
  float s = sumsq;
  s += __shfl_xor(s, 1, 64);
  s += __shfl_xor(s, 2, 64);
  if (mchunk == 0) rmn[n0 + mrow] = (s > 0.f) ? rsqrtf(s) : 0.f;

  // store bf16 dots
#pragma unroll
  for (int i = 0; i < 4; ++i)
#pragma unroll
    for (int j = 0; j < 4; ++j)
#pragma unroll
      for (int r = 0; r < 4; ++r) {
        int q = wave * 64 + i * 16 + quad * 4 + r;
        int n = n0 + j * 16 + l15;
        sims[(size_t)q * Npitch + n] = f2bf(acc[i][j][r]);
      }
}

// ---------------- helpers ----------------
__device__ __forceinline__ bool better(float v1, int i1, float v2, int i2) {
  return v1 > v2 || (v1 == v2 && i1 < i2);
}

template <int L>
__device__ __forceinline__ void insert_topL(float (&tv)[L], int (&ti)[L],
                                            float v, int idx) {
  if (v > tv[L - 1] || (v == tv[L - 1] && idx < ti[L - 1])) {
    tv[L - 1] = v; ti[L - 1] = idx;
#pragma unroll
    for (int j = L - 1; j > 0; --j) {
      if (better(tv[j], ti[j], tv[j - 1], ti[j - 1])) {
        float fv = tv[j]; tv[j] = tv[j - 1]; tv[j - 1] = fv;
        int ii = ti[j]; ti[j] = ti[j - 1]; ti[j - 1] = ii;
      }
    }
  }
}

// ---------------- fused select (bf16 global top-48) + fp32 rescore ---------
// One block per query, 512 threads (8 waves).
// Phase 1: thread-local top-8 over the sims row; 48-round block tournament.
//   Exactness: fp32-top-16 is contained in bf16-top-48 (bf16 cos error
//   ~1.3e-4 vs rank16->rank48 gap ~3e-3 for N=100k gaussian sims); per-thread
//   top-8 prefilter fails only if one thread owns >=9 of the bf16-top-48
//   (P ~ 1e-14 at ~196 elems/thread).
// Phase 2: fp32 rescore of the 48 candidate rows (8 waves x 6 rows),
//   then final top-16 merge in wave 0.
__global__ __launch_bounds__(512) void select_rescore(
    const unsigned short* __restrict__ sims, const float* __restrict__ rmn,
    const float* __restrict__ Q, const float* __restrict__ M,
    const float* __restrict__ qn, float* __restrict__ out,
    int N, int Npitch) {
  __shared__ float s_v[8];
  __shared__ int s_i[8];
  __shared__ int s_t[8];
  __shared__ float s_wv;
  __shared__ int s_wi;
  __shared__ int s_wt;
  __shared__ float cosv[NCAND];
  __shared__ int cidx[NCAND];

  const int q = blockIdx.x;
  const int tid = threadIdx.x;
  const int lane = tid & 63, wave = tid >> 6;

  // ---- phase 1a: thread-local top-8 scan ----
  float tv[8]; int ti[8];
#pragma unroll
  for (int j = 0; j < 8; ++j) { tv[j] = -INFINITY; ti[j] = 0x7fffffff; }
  const unsigned short* row = sims + (size_t)q * Npitch;
  int base = tid * 8;
  for (; base + 8 <= N; base += 4096) {
    uint4 wv = *(const uint4*)(row + base);
    float4 r0 = *(const float4*)&rmn[base];
    float4 r1 = *(const float4*)&rmn[base + 4];
    float f0 = bf2f((unsigned short)(wv.x & 0xffff)) * r0.x;
    float f1 = bf2f((unsigned short)(wv.x >> 16)) * r0.y;
    float f2 = bf2f((unsigned short)(wv.y & 0xffff)) * r0.z;
    float f3 = bf2f((unsigned short)(wv.y >> 16)) * r0.w;
    float f4 = bf2f((unsigned short)(wv.z & 0xffff)) * r1.x;
    float f5 = bf2f((unsigned short)(wv.z >> 16)) * r1.y;
    float f6 = bf2f((unsigned short)(wv.w & 0xffff)) * r1.z;
    float f7 = bf2f((unsigned short)(wv.w >> 16)) * r1.w;
    insert_topL<8>(tv, ti, f0, base + 0);
    insert_topL<8>(tv, ti, f1, base + 1);
    insert_topL<8>(tv, ti, f2, base + 2);
    insert_topL<8>(tv, ti, f3, base + 3);
    insert_topL<8>(tv, ti, f4, base + 4);
    insert_topL<8>(tv, ti, f5, base + 5);
    insert_topL<8>(tv, ti, f6, base + 6);
    insert_topL<8>(tv, ti, f7, base + 7);
  }
  if (base < N) {
    for (int n = base; n < N; ++n)
      insert_topL<8>(tv, ti, bf2f(row[n]) * rmn[n], n);
  }

  // ---- phase 1b: 48-round block tournament over 512 threads ----
  for (int r = 0; r < NCAND; ++r) {
    float v = tv[0];
    int idx = ti[0];
    int src = tid;
#pragma unroll
    for (int o = 32; o > 0; o >>= 1) {
      float ov = __shfl_down(v, o, 64);
      int oi = __shfl_down(idx, o, 64);
      int os = __shfl_down(src, o, 64);
      if (better(ov, oi, v, idx)) { v = ov; idx = oi; src = os; }
    }
    if (lane == 0) { s_v[wave] = v; s_i[wave] = idx; s_t[wave] = src; }
    __syncthreads();
    if (tid == 0) {
      float bv = s_v[0]; int bi = s_i[0]; int bt = s_t[0];
      for (int w2 = 1; w2 < 8; ++w2)
        if (better(s_v[w2], s_i[w2], bv, bi)) { bv = s_v[w2]; bi = s_i[w2]; bt = s_t[w2]; }
      s_wv = bv; s_wi = bi; s_wt = bt;
      cidx[r] = (bi == 0x7fffffff) ? 0 : bi;
    }
    __syncthreads();
    if (tid == s_wt) {
#pragma unroll
      for (int j = 0; j < 7; ++j) { tv[j] = tv[j + 1]; ti[j] = ti[j + 1]; }
      tv[7] = -INFINITY; ti[7] = 0x7fffffff;
    }
    __syncthreads();
  }

  // ---- phase 2: fp32 rescore of 48 candidates (8 waves x 6 rows) ----
  const float4* qf4 = (const float4*)(Q + (size_t)q * DDIM);
  float4 qv[4];
#pragma unroll
  for (int t = 0; t < 4; ++t) qv[t] = qf4[t * 64 + lane];
  float qnv = qn[q];
#pragma unroll 2
  for (int i = 0; i < NCAND / 8; ++i) {
    int c = wave * (NCAND / 8) + i;
    int idx = cidx[c];
    if (idx < 0 || idx >= N) idx = 0;
    const float4* mf4 = (const float4*)(M + (size_t)idx * DDIM);
    float dot = 0.f, sq = 0.f;
#pragma unroll
    for (int t = 0; t < 4; ++t) {
      float4 m = mf4[t * 64 + lane];
      dot += m.x * qv[t].x + m.y * qv[t].y + m.z * qv[t].z + m.w * qv[t].w;
      sq += m.x * m.x + m.y * m.y + m.z * m.z + m.w * m.w;
    }
#pragma unroll
    for (int o = 32; o > 0; o >>= 1) {
      dot += __shfl_down(dot, o, 64);
      sq += __shfl_down(sq, o, 64);
    }
    if (lane == 0) {
      cosv[c] = dot / fmaxf(qnv * sqrtf(sq), EPSV);
    }
  }
  __syncthreads();

  // ---- final top-16 of 48 in wave 0 ----
  if (wave == 0) {
    float v0 = (lane < NCAND) ? cosv[lane] : -INFINITY;
    int i0 = (lane < NCAND) ? cidx[lane] : 0x7fffffff;
    for (int r = 0; r < 16; ++r) {
      float bv = v0;
      int bi = i0;
      int bs = lane;
#pragma unroll
      for (int o = 32; o > 0; o >>= 1) {
        float ov = __shfl_down(bv, o, 64);
        int oi = __shfl_down(bi, o, 64);
        int os = __shfl_down(bs, o, 64);
        if (better(ov, oi, bv, bi)) { bv = ov; bi = oi; bs = os; }
      }
      bv = __shfl(bv, 0, 64);
      bi = __shfl(bi, 0, 64);
      bs = __shfl(bs, 0, 64);
      if (lane == bs) v0 = -INFINITY;
      if (lane == 0) {
        out[(size_t)q * 16 + r] = bv;
        out[(size_t)BQ * 16 + (size_t)q * 16 + r] = (float)bi;
      }
    }
  }
}

extern "C" void kernel_launch(void* const* d_in, const int* in_sizes, int n_in,
                              void* d_out, int out_size, void* d_ws, size_t ws_size,
                              hipStream_t stream) {
  const float* Q = (const float*)d_in[0];
  const float* M = (const float*)d_in[1];
  int N = in_sizes[1] / DDIM;
  float* out = (float*)d_out;

  int nb = (N + 63) / 64;
  int Npitch = nb * 64;

  char* w = (char*)d_ws;
  size_t off = 0;
  auto alloc = [&](size_t bytes) {
    char* p = w + off;
    off = (off + bytes + 255) & ~(size_t)255;
    return p;
  };
  unsigned short* Qb = (unsigned short*)alloc((size_t)BQ * DDIM * 2);
  float* qn = (float*)alloc((size_t)BQ * 4);
  float* rmn = (float*)alloc((size_t)Npitch * 4);
  unsigned short* sims = (unsigned short*)alloc((size_t)BQ * Npitch * 2);
  (void)ws_size;

  prep_q<<<BQ / 4, 256, 0, stream>>>(Q, Qb, qn);
  gemm_topk<<<nb, 256, 0, stream>>>(M, Qb, sims, rmn, N, Npitch);
  select_rescore<<<BQ, 512, 0, stream>>>(sims, rmn, Q, M, qn, out, N, Npitch);
}

// Round 4
// 676.319 us; speedup vs baseline: 1.0675x; 1.0675x over previous
//
#include <hip/hip_runtime.h>
#include <math.h>

#define DDIM 1024
#define BQ 256
#define EPSV 1e-8f
#define CH 4
#define TPC 16
#define NCAND (CH * TPC)

typedef short bf16x8 __attribute__((ext_vector_type(8)));
typedef float f32x4 __attribute__((ext_vector_type(4)));

__device__ __forceinline__ unsigned short f2bf(float x) {
  union { float f; unsigned int u; } v;
  v.f = x;
  unsigned int lsb = (v.u >> 16) & 1u;
  v.u += 0x7fffu + lsb;  // round-to-nearest-even
  return (unsigned short)(v.u >> 16);
}
__device__ __forceinline__ float bf2f(unsigned short b) {
  union { unsigned int u; float f; } v;
  v.u = ((unsigned int)b) << 16;
  return v.f;
}
// packed fp32->bf16 (RNE), 1 instr for 2 elements: low16=bf16(lo), hi16=bf16(hi)
__device__ __forceinline__ unsigned int cvtpk_bf16(float lo, float hi) {
  unsigned int r;
  asm("v_cvt_pk_bf16_f32 %0, %1, %2" : "=v"(r) : "v"(lo), "v"(hi));
  return r;
}

// ---------------- prep: Q fp32 -> bf16 in MFMA-fragment order, qn ----------
// Qb layout: 16-B chunks. chunk = (t*16 + q/16)*64 + kquad*16 + (q&15),
// where t = k/32, kquad = (k/8)&3, elem = k&7. With this order, the gemm
// wave's fragment load group (t, g=w*4+i) has lane l reading chunk
// group*64 + l  == one contiguous, perfectly coalesced 1 KB per wave.
__global__ __launch_bounds__(256) void prep_q(const float* __restrict__ Q,
                                              unsigned short* __restrict__ Qb,
                                              float* __restrict__ qn) {
  int wave = threadIdx.x >> 6, lane = threadIdx.x & 63;
  int q = blockIdx.x * 4 + wave;
  const float4* src = (const float4*)(Q + (size_t)q * DDIM);
  int g = q >> 4, qrow = q & 15;
  float s = 0.f;
#pragma unroll
  for (int t4 = 0; t4 < 4; ++t4) {
    float4 v = src[t4 * 64 + lane];
    s += v.x * v.x + v.y * v.y + v.z * v.z + v.w * v.w;
    int k = t4 * 256 + lane * 4;
    int tt = k >> 5;
    int kquad = (k >> 3) & 3;
    int elem = k & 7;  // 0 or 4
    size_t chunk = (size_t)(tt * 16 + g) * 64 + kquad * 16 + qrow;
    ushort4 o;
    o.x = f2bf(v.x); o.y = f2bf(v.y); o.z = f2bf(v.z); o.w = f2bf(v.w);
    *(ushort4*)(Qb + chunk * 8 + elem) = o;
  }
#pragma unroll
  for (int o = 32; o > 0; o >>= 1) s += __shfl_down(s, o, 64);
  if (lane == 0) qn[q] = sqrtf(s);
}

// ---------------- MFMA GEMM: all 256 q x 64 n per block ----------------
// Q comes straight from L2-resident fragment-ordered Qb into registers
// (double-buffered, prefetched one step ahead) — NO Q LDS staging. LDS holds
// only the 64x32 M tile (double-buffered, 8 KB). One raw barrier per K-step;
// all global loads are compiler-visible so vmcnt waits are auto-counted and
// the in-flight prefetches (M(t+2) x2 + Q(t+1) x4) survive the barrier.
// Epilogue folds 1/||m|| into the stored sims (bf16 of the cosine), so the
// selection pass needs no separate rmn array.
__global__ __launch_bounds__(256) void gemm_topk(
    const float* __restrict__ M, const unsigned short* __restrict__ Qb,
    unsigned short* __restrict__ sims, int N, int Npitch) {
  __shared__ unsigned short Ms[2][64 * 32];  // [buf][n][k]
  __shared__ float rls[64];                  // 1/||m|| for this block's rows
  const int tid = threadIdx.x;
  const int wave = tid >> 6, lane = tid & 63;
  const int quad = lane >> 4, l15 = lane & 15;
  const int n0 = blockIdx.x * 64;

  const int mrow = tid >> 2;    // 0..63
  const int mchunk = tid & 3;   // 0..3, 8 floats each
  const bool mvalid = (n0 + mrow) < N;
  // invalid rows redirect to row 0: keeps vmem issue counts wave-uniform;
  // resulting sims at n>=N land in the pitch padding and are never read.
  const float* mptr = M + (size_t)(mvalid ? (n0 + mrow) : 0) * DDIM + mchunk * 8;

  // fragment pointer: afr(t, i) = qptr[t*1024 + i*64]
  const bf16x8* qptr = (const bf16x8*)Qb + (size_t)wave * 256 + lane;

  f32x4 acc[4][4];
#pragma unroll
  for (int i = 0; i < 4; ++i)
#pragma unroll
    for (int j = 0; j < 4; ++j) acc[i][j] = (f32x4){0.f, 0.f, 0.f, 0.f};
  float sumsq = 0.f;

  // prologue: Q(0) fragments + M(0), M(1) into named reg sets.
  bf16x8 aA0 = qptr[0], aA1 = qptr[64], aA2 = qptr[128], aA3 = qptr[192];
  bf16x8 aB0{}, aB1{}, aB2{}, aB3{};  // filled by body(0) before body(1) reads
  float4 mrA0 = *(const float4*)(mptr);
  float4 mrA1 = *(const float4*)(mptr + 4);
  float4 mrB0 = *(const float4*)(mptr + 32);
  float4 mrB1 = *(const float4*)(mptr + 36);

  auto body = [&](int t, int buf, float4& r0, float4& r1, bf16x8& c0,
                  bf16x8& c1, bf16x8& c2, bf16x8& c3, bf16x8& p0, bf16x8& p1,
                  bf16x8& p2, bf16x8& p3) {
    // ---- convert M(t) -> Ms[buf], sumsq, prefetch M(t+2) ----
    sumsq += r0.x * r0.x + r0.y * r0.y + r0.z * r0.z + r0.w * r0.w +
             r1.x * r1.x + r1.y * r1.y + r1.z * r1.z + r1.w * r1.w;
    uint4 packed;
    packed.x = cvtpk_bf16(r0.x, r0.y);
    packed.y = cvtpk_bf16(r0.z, r0.w);
    packed.z = cvtpk_bf16(r1.x, r1.y);
    packed.w = cvtpk_bf16(r1.z, r1.w);
    *(uint4*)&Ms[buf][mrow * 32 + mchunk * 8] = packed;
    int k2 = t * 32 + 64;
    const float* p = mptr + ((k2 < DDIM) ? k2 : 0);  // dummy keeps count uniform
    r0 = *(const float4*)(p);
    r1 = *(const float4*)(p + 4);
    // ---- Ms[buf] visible to all waves; prefetches stay in flight ----
    asm volatile("s_waitcnt lgkmcnt(0)" ::: "memory");
    __builtin_amdgcn_s_barrier();
    __builtin_amdgcn_sched_barrier(0);
    // ---- prefetch Q(t+1) fragments (dummy reload of group 0 at t=31) ----
    const bf16x8* qp = qptr + (size_t)((t + 1) & 31) * 1024;
    p0 = qp[0]; p1 = qp[64]; p2 = qp[128]; p3 = qp[192];
    // ---- compute on buf with current Q fragments ----
    bf16x8 bfr[4];
#pragma unroll
    for (int j = 0; j < 4; ++j)
      bfr[j] = *(const bf16x8*)&Ms[buf][(j * 16 + l15) * 32 + quad * 8];
    acc[0][0] = __builtin_amdgcn_mfma_f32_16x16x32_bf16(c0, bfr[0], acc[0][0], 0, 0, 0);
    acc[0][1] = __builtin_amdgcn_mfma_f32_16x16x32_bf16(c0, bfr[1], acc[0][1], 0, 0, 0);
    acc[0][2] = __builtin_amdgcn_mfma_f32_16x16x32_bf16(c0, bfr[2], acc[0][2], 0, 0, 0);
    acc[0][3] = __builtin_amdgcn_mfma_f32_16x16x32_bf16(c0, bfr[3], acc[0][3], 0, 0, 0);
    acc[1][0] = __builtin_amdgcn_mfma_f32_16x16x32_bf16(c1, bfr[0], acc[1][0], 0, 0, 0);
    acc[1][1] = __builtin_amdgcn_mfma_f32_16x16x32_bf16(c1, bfr[1], acc[1][1], 0, 0, 0);
    acc[1][2] = __builtin_amdgcn_mfma_f32_16x16x32_bf16(c1, bfr[2], acc[1][2], 0, 0, 0);
    acc[1][3] = __builtin_amdgcn_mfma_f32_16x16x32_bf16(c1, bfr[3], acc[1][3], 0, 0, 0);
    acc[2][0] = __builtin_amdgcn_mfma_f32_16x16x32_bf16(c2, bfr[0], acc[2][0], 0, 0, 0);
    acc[2][1] = __builtin_amdgcn_mfma_f32_16x16x32_bf16(c2, bfr[1], acc[2][1], 0, 0, 0);
    acc[2][2] = __builtin_amdgcn_mfma_f32_16x16x32_bf16(c2, bfr[2], acc[2][2], 0, 0, 0);
    acc[2][3] = __builtin_amdgcn_mfma_f32_16x16x32_bf16(c2, bfr[3], acc[2][3], 0, 0, 0);
    acc[3][0] = __builtin_amdgcn_mfma_f32_16x16x32_bf16(c3, bfr[0], acc[3][0], 0, 0, 0);
    acc[3][1] = __builtin_amdgcn_mfma_f32_16x16x32_bf16(c3, bfr[1], acc[3][1], 0, 0, 0);
    acc[3][2] = __builtin_amdgcn_mfma_f32_16x16x32_bf16(c3, bfr[2], acc[3][2], 0, 0, 0);
    acc[3][3] = __builtin_amdgcn_mfma_f32_16x16x32_bf16(c3, bfr[3], acc[3][3], 0, 0, 0);
  };

#pragma unroll 1
  for (int t = 0; t < 32; t += 2) {
    body(t, 0, mrA0, mrA1, aA0, aA1, aA2, aA3, aB0, aB1, aB2, aB3);
    body(t + 1, 1, mrB0, mrB1, aB0, aB1, aB2, aB3, aA0, aA1, aA2, aA3);
  }

  // 1/||m|| for this block's 64 rows (exact fp32 sums from staging data),
  // staged in LDS so every thread can fold it into its stored sims.
  float s = sumsq;
  s += __shfl_xor(s, 1, 64);
  s += __shfl_xor(s, 2, 64);
  if (mchunk == 0) rls[mrow] = (s > 0.f) ? rsqrtf(s) : 0.f;
  __syncthreads();

  // store bf16 cosines (dot * 1/||m||; 1/||q||=1 folding not needed since
  // per-q positive scaling does not change per-q ranking, and rescore
  // recomputes exact fp32 cos anyway)
#pragma unroll
  for (int j = 0; j < 4; ++j) {
    float rm = rls[j * 16 + l15];
#pragma unroll
    for (int i = 0; i < 4; ++i)
#pragma unroll
      for (int r = 0; r < 4; ++r) {
        int q = wave * 64 + i * 16 + quad * 4 + r;
        int n = n0 + j * 16 + l15;
        sims[(size_t)q * Npitch + n] = f2bf(acc[i][j][r] * rm);
      }
  }
}

// ---------------- helpers ----------------
__device__ __forceinline__ bool better(float v1, int i1, float v2, int i2) {
  return v1 > v2 || (v1 == v2 && i1 < i2);
}

template <int L>
__device__ __forceinline__ void insert_topL(float (&tv)[L], int (&ti)[L],
                                            float v, int idx) {
  if (v > tv[L - 1] || (v == tv[L - 1] && idx < ti[L - 1])) {
    tv[L - 1] = v; ti[L - 1] = idx;
#pragma unroll
    for (int j = L - 1; j > 0; --j) {
      if (better(tv[j], ti[j], tv[j - 1], ti[j - 1])) {
        float fv = tv[j]; tv[j] = tv[j - 1]; tv[j - 1] = fv;
        int ii = ti[j]; ti[j] = ti[j - 1]; ti[j - 1] = ii;
      }
    }
  }
}

// block tournament (blockDim=256): extract `rounds` best entries across
// per-thread sorted lists of length L.
template <int L, typename F>
__device__ __forceinline__ void block_extract(float (&tv)[L], int (&ti)[L],
                                              int rounds, F&& emit) {
  __shared__ float s_v[4];
  __shared__ int s_i[4];
  __shared__ int s_t[4];
  __shared__ float s_wv;
  __shared__ int s_wi;
  __shared__ int s_wt;
  for (int r = 0; r < rounds; ++r) {
    float v = tv[0];
    int idx = ti[0];
    int src = threadIdx.x;
#pragma unroll
    for (int o = 32; o > 0; o >>= 1) {
      float ov = __shfl_down(v, o, 64);
      int oi = __shfl_down(idx, o, 64);
      int os = __shfl_down(src, o, 64);
      if (better(ov, oi, v, idx)) { v = ov; idx = oi; src = os; }
    }
    int lane = threadIdx.x & 63, w = threadIdx.x >> 6;
    if (lane == 0) { s_v[w] = v; s_i[w] = idx; s_t[w] = src; }
    __syncthreads();
    if (threadIdx.x == 0) {
      float bv = s_v[0]; int bi = s_i[0]; int bt = s_t[0];
      for (int w2 = 1; w2 < 4; ++w2)
        if (better(s_v[w2], s_i[w2], bv, bi)) { bv = s_v[w2]; bi = s_i[w2]; bt = s_t[w2]; }
      s_wv = bv; s_wi = bi; s_wt = bt;
    }
    __syncthreads();
    if (threadIdx.x == s_wt) {
#pragma unroll
      for (int j = 0; j < L - 1; ++j) { tv[j] = tv[j + 1]; ti[j] = ti[j + 1]; }
      tv[L - 1] = -INFINITY; ti[L - 1] = 0x7fffffff;
    }
    if (threadIdx.x == 0) emit(r, s_wv, s_wi);
    __syncthreads();
  }
}

// ---------------- selection: per (q, chunk) top-16 by bf16 cos ----------------
// sims is already cosine-scaled (rmn folded at gemm store), so the scan is a
// pure bf16 load + compare stream: 16 B per 8 elements.
__global__ __launch_bounds__(256) void select_chunks(
    const unsigned short* __restrict__ sims, int* __restrict__ cand,
    int N, int Npitch, int Nc) {
  int q = blockIdx.y;
  int c = blockIdx.x;
  int start = c * Nc;
  int end = start + Nc;
  if (end > N) end = N;
  float tv[8]; int ti[8];
#pragma unroll
  for (int j = 0; j < 8; ++j) { tv[j] = -INFINITY; ti[j] = 0x7fffffff; }
  const unsigned short* row = sims + (size_t)q * Npitch;
  int base = start + threadIdx.x * 8;
  for (; base + 8 <= end; base += 2048) {
    uint4 wv = *(const uint4*)(row + base);
    float f0 = bf2f((unsigned short)(wv.x & 0xffff));
    float f1 = bf2f((unsigned short)(wv.x >> 16));
    float f2 = bf2f((unsigned short)(wv.y & 0xffff));
    float f3 = bf2f((unsigned short)(wv.y >> 16));
    float f4 = bf2f((unsigned short)(wv.z & 0xffff));
    float f5 = bf2f((unsigned short)(wv.z >> 16));
    float f6 = bf2f((unsigned short)(wv.w & 0xffff));
    float f7 = bf2f((unsigned short)(wv.w >> 16));
    insert_topL<8>(tv, ti, f0, base + 0);
    insert_topL<8>(tv, ti, f1, base + 1);
    insert_topL<8>(tv, ti, f2, base + 2);
    insert_topL<8>(tv, ti, f3, base + 3);
    insert_topL<8>(tv, ti, f4, base + 4);
    insert_topL<8>(tv, ti, f5, base + 5);
    insert_topL<8>(tv, ti, f6, base + 6);
    insert_topL<8>(tv, ti, f7, base + 7);
  }
  // ragged tail
  if (base < end) {
    for (int n = base; n < end; ++n)
      insert_topL<8>(tv, ti, bf2f(row[n]), n);
  }
  int* dst = cand + (size_t)q * NCAND + c * TPC;
  block_extract<8>(tv, ti, TPC, [&](int r, float v, int i) {
    dst[r] = (i == 0x7fffffff) ? 0 : i;
  });
}

// ---------------- rescore candidates in fp32, final top-16 ----------------
__global__ __launch_bounds__(512) void rescore(
    const float* __restrict__ Q, const float* __restrict__ M,
    const float* __restrict__ qn, const int* __restrict__ cand,
    float* __restrict__ out, int N) {
  __shared__ float cosv[NCAND];
  __shared__ int cidx[NCAND];
  int q = blockIdx.x;
  int wave = threadIdx.x >> 6, lane = threadIdx.x & 63;
  const float4* qf4 = (const float4*)(Q + (size_t)q * DDIM);
  float4 qv[4];
#pragma unroll
  for (int t = 0; t < 4; ++t) qv[t] = qf4[t * 64 + lane];
  float qnv = qn[q];
#pragma unroll 1
  for (int i = 0; i < NCAND / 8; ++i) {
    int c = wave * (NCAND / 8) + i;
    int idx = cand[(size_t)q * NCAND + c];
    if (idx < 0 || idx >= N) idx = 0;
    const float4* mf4 = (const float4*)(M + (size_t)idx * DDIM);
    float dot = 0.f, sq = 0.f;
#pragma unroll
    for (int t = 0; t < 4; ++t) {
      float4 m = mf4[t * 64 + lane];
      dot += m.x * qv[t].x + m.y * qv[t].y + m.z * qv[t].z + m.w * qv[t].w;
      sq += m.x * m.x + m.y * m.y + m.z * m.z + m.w * m.w;
    }
#pragma unroll
    for (int o = 32; o > 0; o >>= 1) {
      dot += __shfl_down(dot, o, 64);
      sq += __shfl_down(sq, o, 64);
    }
    if (lane == 0) {
      cosv[c] = dot / fmaxf(qnv * sqrtf(sq), EPSV);
      cidx[c] = idx;
    }
  }
  __syncthreads();
  // final top-16 of the 64 candidates in wave 0
  if (wave == 0) {
    float v0 = cosv[lane];
    int i0 = cidx[lane];
    for (int r = 0; r < 16; ++r) {
      float bv = v0;
      int bi = i0;
      int bs = lane;
#pragma unroll
      for (int o = 32; o > 0; o >>= 1) {
        float ov = __shfl_down(bv, o, 64);
        int oi = __shfl_down(bi, o, 64);
        int os = __shfl_down(bs, o, 64);
        if (better(ov, oi, bv, bi)) { bv = ov; bi = oi; bs = os; }
      }
      bv = __shfl(bv, 0, 64);
      bi = __shfl(bi, 0, 64);
      bs = __shfl(bs, 0, 64);
      if (lane == bs) v0 = -INFINITY;
      if (lane == 0) {
        out[(size_t)q * 16 + r] = bv;
        out[(size_t)BQ * 16 + (size_t)q * 16 + r] = (float)bi;
      }
    }
  }
}

extern "C" void kernel_launch(void* const* d_in, const int* in_sizes, int n_in,
                              void* d_out, int out_size, void* d_ws, size_t ws_size,
                              hipStream_t stream) {
  const float* Q = (const float*)d_in[0];
  const float* M = (const float*)d_in[1];
  int N = in_sizes[1] / DDIM;
  float* out = (float*)d_out;

  int nb = (N + 63) / 64;
  int Npitch = nb * 64;

  char* w = (char*)d_ws;
  size_t off = 0;
  auto alloc = [&](size_t bytes) {
    char* p = w + off;
    off = (off + bytes + 255) & ~(size_t)255;
    return p;
  };
  unsigned short* Qb = (unsigned short*)alloc((size_t)BQ * DDIM * 2);
  float* qn = (float*)alloc((size_t)BQ * 4);
  int* cand = (int*)alloc((size_t)BQ * NCAND * 4);
  unsigned short* sims = (unsigned short*)alloc((size_t)BQ * Npitch * 2);
  (void)ws_size;

  int Nc = (((N + CH - 1) / CH) + 7) & ~7;

  prep_q<<<BQ / 4, 256, 0, stream>>>(Q, Qb, qn);
  gemm_topk<<<nb, 256, 0, stream>>>(M, Qb, sims, N, Npitch);
  select_chunks<<<dim3(CH, BQ), 256, 0, stream>>>(sims, cand, N, Npitch, Nc);
  rescore<<<BQ, 512, 0, stream>>>(Q, M, qn, cand, out, N);
}